// Round 8
// baseline (188.465 us; speedup 1.0000x reference)
//
#include <hip/hip_runtime.h>
#include <hip/hip_bf16.h>

#define EMBED 1536
#define SEQ   896
#define NOUT  5313

#define N0 5313
#define N1 1643
#define N2 128

#define LN_BLOCKS 1792           // 2 rows per block, 4*896 rows
#define GEMM_GRID 1280           // >= worst-case R (1176); surplus blocks do zero-fill

typedef __attribute__((ext_vector_type(8))) short bf16x8;   // 8 bf16 = 4 VGPRs
typedef __attribute__((ext_vector_type(4))) float f32x4;

__device__ __forceinline__ void gload_lds16(const void* g, void* l) {
    __builtin_amdgcn_global_load_lds(
        (const __attribute__((address_space(1))) void*)g,
        (__attribute__((address_space(3))) void*)l, 16, 0, 0);
}

__device__ __forceinline__ int tiles_of(int h) {
    return (h == 0) ? 42 : (h == 1) ? 13 : (h == 2) ? 1 : 0;
}
__device__ __forceinline__ int nrows_of(int h) {
    return (h == 0) ? N0 : (h == 1) ? N1 : (h == 2) ? N2 : 0;
}

// ---- 1) prep: LayerNorm fp32 -> bf16 xn (two rows per block) ----
__global__ __launch_bounds__(256) void ln_kernel(
    const float* __restrict__ x, const int* __restrict__ head_idx,
    const float* __restrict__ g0, const float* __restrict__ be0,
    const float* __restrict__ g1, const float* __restrict__ be1,
    const float* __restrict__ g2, const float* __restrict__ be2,
    __hip_bfloat16* __restrict__ xn)
{
    const int tid = threadIdx.x;
    const int half = tid >> 7;               // 0 or 1
    const int lt   = tid & 127;
    const int row  = blockIdx.x * 2 + half;  // rows 2i, 2i+1: same batch (896 even)
    const int b    = row / SEQ;
    const int h    = head_idx[b];
    if (h == 3) return;                      // block-uniform: ZeroHead batch, xn unused

    const float* gamma = (h == 1) ? g1 : (h == 2) ? g2 : g0;
    const float* beta  = (h == 1) ? be1 : (h == 2) ? be2 : be0;
    const float* xr = x + (size_t)row * EMBED;

    float4 v[3];
    float sum = 0.f, sq = 0.f;
#pragma unroll
    for (int i = 0; i < 3; ++i) {
        v[i] = ((const float4*)xr)[lt + i * 128];
        sum += v[i].x + v[i].y + v[i].z + v[i].w;
        sq  += v[i].x * v[i].x + v[i].y * v[i].y + v[i].z * v[i].z + v[i].w * v[i].w;
    }
#pragma unroll
    for (int off = 32; off > 0; off >>= 1) {
        sum += __shfl_down(sum, off);
        sq  += __shfl_down(sq, off);
    }
    __shared__ float s_sum[4], s_sq[4];
    const int wave = tid >> 6, lane = tid & 63;
    if (lane == 0) { s_sum[wave] = sum; s_sq[wave] = sq; }
    __syncthreads();
    const int wb = half << 1;
    const float mu  = (s_sum[wb] + s_sum[wb + 1]) * (1.f / EMBED);
    const float var = (s_sq[wb] + s_sq[wb + 1]) * (1.f / EMBED) - mu * mu;
    const float rs  = rsqrtf(var + 1e-5f);

    __hip_bfloat16* xo = xn + (size_t)row * EMBED;
#pragma unroll
    for (int i = 0; i < 3; ++i) {
        const int idx = lt + i * 128;
        float4 gv = ((const float4*)gamma)[idx];
        float4 bv = ((const float4*)beta)[idx];
        union { __hip_bfloat16 h4[4]; short4 s4; } u;
        u.h4[0] = __float2bfloat16((v[i].x - mu) * rs * gv.x + bv.x);
        u.h4[1] = __float2bfloat16((v[i].y - mu) * rs * gv.y + bv.y);
        u.h4[2] = __float2bfloat16((v[i].z - mu) * rs * gv.z + bv.z);
        u.h4[3] = __float2bfloat16((v[i].w - mu) * rs * gv.w + bv.w);
        ((short4*)xo)[idx] = u.s4;
    }
}

// ---- 2) bf16 MFMA GEMM (128x128, compacted); B staged from fp32 W directly ----
// ids 0..R-1: real tiles. ids >= R: zero-fill invalid col ranges (backfill idle CUs).
__global__ __launch_bounds__(256, 2) void head_gemm(
    const __hip_bfloat16* __restrict__ xn,   // (4*896, 1536) layernormed
    const float* __restrict__ W0, const float* __restrict__ W1,
    const float* __restrict__ W2,
    const float* __restrict__ b0, const float* __restrict__ b1,
    const float* __restrict__ b2,
    const int* __restrict__ head_idx,
    float* __restrict__ out)                 // (4, 896, 5313)
{
    const int h0 = head_idx[0], h1 = head_idx[1];
    const int h2 = head_idx[2], h3 = head_idx[3];
    const int t0 = tiles_of(h0) * 7, t1 = tiles_of(h1) * 7;
    const int t2 = tiles_of(h2) * 7, t3 = tiles_of(h3) * 7;
    const int R = t0 + t1 + t2 + t3;
    const int tid = threadIdx.x;

    if ((int)blockIdx.x >= R) {
        // ---- zero-fill: strided rows over the invalid column ranges ----
        const int j = blockIdx.x - R;
        const int ZB = GEMM_GRID - R;            // >=104 whenever zf is needed
        for (int row = j; row < 4 * SEQ; row += ZB) {
            const int b = row / SEQ;
            const int h = (b == 0) ? h0 : (b == 1) ? h1 : (b == 2) ? h2 : h3;
            const int n = nrows_of(h);
            if (n >= NOUT) continue;
            float* o = out + (size_t)row * NOUT;
            const int pre0 = (4 - (int)(((size_t)row * NOUT + n) & 3)) & 3;
            const int pre_end = min(n + pre0, NOUT);
            for (int c = n + tid; c < pre_end; c += 256) o[c] = 0.f;
            const int nvec = (NOUT - pre_end) >> 2;
            const float4 z = make_float4(0.f, 0.f, 0.f, 0.f);
            float4* ov = (float4*)(o + pre_end);
            for (int i = tid; i < nvec; i += 256) ov[i] = z;
            for (int c = pre_end + (nvec << 2) + tid; c < NOUT; c += 256) o[c] = 0.f;
        }
        return;
    }

    int rem = blockIdx.x, b;
    if (rem < t0)                { b = 0; }
    else if (rem < t0 + t1)      { b = 1; rem -= t0; }
    else if (rem < t0 + t1 + t2) { b = 2; rem -= t0 + t1; }
    else                         { b = 3; rem -= t0 + t1 + t2; }

    const int h = (b == 0) ? h0 : (b == 1) ? h1 : (b == 2) ? h2 : h3;
    const int ntc = tiles_of(h);
    const int mt = rem / ntc;                    // 0..6 (128-row M tiles)
    const int nt = rem - mt * ntc;               // nt fastest: consecutive ids share A
    const int nrows = nrows_of(h);
    const float* __restrict__ Wh = (h == 0) ? W0 : (h == 1) ? W1 : W2;

    const int col0 = nt * 128;
    float* outb = out + ((size_t)b * SEQ + (size_t)mt * 128) * NOUT;

    __shared__ __hip_bfloat16 As[128 * 64];   // 16 KB
    __shared__ __hip_bfloat16 Bs[128 * 64];   // 16 KB
    const __hip_bfloat16* Ab = xn + ((size_t)b * SEQ + (size_t)mt * 128) * EMBED;

    const int wave = tid >> 6, lane = tid & 63;
    const int wm = wave >> 1, wn = wave & 1;         // 2x2 waves of 64x64
    const int fm = lane & 15, quad = lane >> 4;
    const int fsw = fm & 7;                          // XOR swizzle key (row & 7)

    // precompute this thread's B-staging coordinates (4 chunks, invariant in kt)
    int bgrow[4], bkc[4], bc[4];
#pragma unroll
    for (int i = 0; i < 4; ++i) {
        const int c = tid + i * 256;
        const int brow = c >> 3;
        bkc[i] = (c & 7) ^ (brow & 7);               // xor-swizzled k-chunk
        bgrow[i] = min(col0 + brow, nrows - 1);      // clamp OOB rows (cols masked later)
        bc[i] = c;
    }

    f32x4 acc[4][4] = {};

    for (int kt = 0; kt < EMBED / 64; ++kt) {        // 24 iterations
        const int k0 = kt * 64;
        __syncthreads();                             // prev readers done
#pragma unroll
        for (int i = 0; i < 4; ++i) {                // stage A: 128x64 bf16 (async->LDS)
            const int c = tid + i * 256;             // LDS chunk 0..1023 (16B each)
            const int arow = c >> 3;
            const int kc = (c & 7) ^ (arow & 7);     // xor-swizzled k-chunk
            gload_lds16(Ab + (size_t)arow * EMBED + k0 + kc * 8, As + c * 8);
        }
#pragma unroll
        for (int i = 0; i < 4; ++i) {                // stage B: fp32 W -> cvt -> LDS
            const float4* wp = (const float4*)(Wh + (size_t)bgrow[i] * EMBED + k0 + bkc[i] * 8);
            float4 a = wp[0], b4 = wp[1];
            union { __hip_bfloat16 h8[8]; int4 v4; } u;
            u.h8[0] = __float2bfloat16(a.x);  u.h8[1] = __float2bfloat16(a.y);
            u.h8[2] = __float2bfloat16(a.z);  u.h8[3] = __float2bfloat16(a.w);
            u.h8[4] = __float2bfloat16(b4.x); u.h8[5] = __float2bfloat16(b4.y);
            u.h8[6] = __float2bfloat16(b4.z); u.h8[7] = __float2bfloat16(b4.w);
            *(int4*)(Bs + bc[i] * 8) = u.v4;
        }
        __syncthreads();                             // drains vmcnt+lgkmcnt before barrier
#pragma unroll
        for (int ks = 0; ks < 2; ++ks) {
            bf16x8 af[4], bfr[4];
#pragma unroll
            for (int i = 0; i < 4; ++i)
                af[i] = *(const bf16x8*)&As[(wm * 64 + i * 16 + fm) * 64 +
                                            (((ks << 2) + quad) ^ fsw) * 8];
#pragma unroll
            for (int j = 0; j < 4; ++j)
                bfr[j] = *(const bf16x8*)&Bs[(wn * 64 + j * 16 + fm) * 64 +
                                             (((ks << 2) + quad) ^ fsw) * 8];
#pragma unroll
            for (int i = 0; i < 4; ++i)
#pragma unroll
                for (int j = 0; j < 4; ++j)
                    acc[i][j] = __builtin_amdgcn_mfma_f32_16x16x32_bf16(
                        af[i], bfr[j], acc[i][j], 0, 0, 0);
        }
    }

    // epilogue: bias + softplus; store ONLY valid cols (zero region owned by zf)
    const float* bias = (h == 1) ? b1 : (h == 2) ? b2 : b0;
#pragma unroll
    for (int j = 0; j < 4; ++j) {
        const int lcol = col0 + wn * 64 + j * 16 + fm;
        const bool valid = lcol < nrows;
        const float bv = valid ? bias[lcol] : 0.f;
#pragma unroll
        for (int i = 0; i < 4; ++i) {
            const int rbase = wm * 64 + i * 16 + quad * 4;
#pragma unroll
            for (int r = 0; r < 4; ++r) {
                const float v = acc[i][j][r] + bv;
                // softplus: max(v,0) + log(1 + exp(-|v|)) — overflow-safe
                const float sp = fmaxf(v, 0.f) + __logf(1.f + __expf(-fabsf(v)));
                if (valid) outb[(size_t)(rbase + r) * NOUT + lcol] = sp;
            }
        }
    }
}

extern "C" void kernel_launch(void* const* d_in, const int* in_sizes, int n_in,
                              void* d_out, int out_size, void* d_ws, size_t ws_size,
                              hipStream_t stream) {
    const float* x   = (const float*)d_in[0];
    const int* hidx  = (const int*)d_in[1];
    const float* g0  = (const float*)d_in[2];
    const float* be0 = (const float*)d_in[3];
    const float* W0  = (const float*)d_in[4];
    const float* b0  = (const float*)d_in[5];
    const float* g1  = (const float*)d_in[6];
    const float* be1 = (const float*)d_in[7];
    const float* W1  = (const float*)d_in[8];
    const float* b1  = (const float*)d_in[9];
    const float* g2  = (const float*)d_in[10];
    const float* be2 = (const float*)d_in[11];
    const float* W2  = (const float*)d_in[12];
    const float* b2  = (const float*)d_in[13];
    float* out = (float*)d_out;

    __hip_bfloat16* xn = (__hip_bfloat16*)d_ws;     // 4*896*1536 bf16 = 11 MB

    ln_kernel<<<LN_BLOCKS, 256, 0, stream>>>(
        x, hidx, g0, be0, g1, be1, g2, be2, xn);
    head_gemm<<<GEMM_GRID, 256, 0, stream>>>(
        xn, W0, W1, W2, b0, b1, b2, hidx, out);
}

// Round 9
// 172.640 us; speedup vs baseline: 1.0917x; 1.0917x over previous
//
#include <hip/hip_runtime.h>
#include <hip/hip_bf16.h>

#define EMBED 1536
#define SEQ   896
#define NOUT  5313

// padded head row layout inside wpad
#define N0 5313
#define N1 1643
#define N2 128
#define W0OFF 0
#define W1OFF 5376
#define W2OFF 7040
#define PTOT  7168

#define LN_BLOCKS 1792           // 2 rows per block, 4*896 rows
#define WC_BLOCKS 5376           // PTOT*1536 bf16 elems / (256 thr * 8 elems)
#define GEMM_GRID 1280           // >= worst-case R (1176); surplus blocks do zero-fill
#define BK 128                   // K-tile: 12 iters, 2x32 KB LDS, halved barrier count

typedef __attribute__((ext_vector_type(8))) short bf16x8;   // 8 bf16 = 4 VGPRs
typedef __attribute__((ext_vector_type(4))) float f32x4;

__device__ __forceinline__ void gload_lds16(const void* g, void* l) {
    __builtin_amdgcn_global_load_lds(
        (const __attribute__((address_space(1))) void*)g,
        (__attribute__((address_space(3))) void*)l, 16, 0, 0);
}

__device__ __forceinline__ int tiles_of(int h) {
    return (h == 0) ? 42 : (h == 1) ? 13 : (h == 2) ? 1 : 0;
}
__device__ __forceinline__ int nrows_of(int h) {
    return (h == 0) ? N0 : (h == 1) ? N1 : (h == 2) ? N2 : 0;
}

// ---- 1) fused prep: LN -> bf16 xn | selective W -> bf16 ----
__global__ __launch_bounds__(256) void prep_kernel(
    const float* __restrict__ x, const int* __restrict__ head_idx,
    const float* __restrict__ g0, const float* __restrict__ be0,
    const float* __restrict__ g1, const float* __restrict__ be1,
    const float* __restrict__ g2, const float* __restrict__ be2,
    const float* __restrict__ W0, const float* __restrict__ W1,
    const float* __restrict__ W2,
    __hip_bfloat16* __restrict__ xn, __hip_bfloat16* __restrict__ wpad)
{
    const int tid = threadIdx.x;

    if (blockIdx.x < LN_BLOCKS) {
        // ---- LayerNorm: two rows per block (one per 128-thread half) ----
        const int half = tid >> 7;               // 0 or 1
        const int lt   = tid & 127;
        const int row  = blockIdx.x * 2 + half;  // rows 2i, 2i+1: same batch (896 even)
        const int b    = row / SEQ;
        const int h    = head_idx[b];
        if (h == 3) return;                      // block-uniform: ZeroHead batch, xn unused

        const float* gamma = (h == 1) ? g1 : (h == 2) ? g2 : g0;
        const float* beta  = (h == 1) ? be1 : (h == 2) ? be2 : be0;
        const float* xr = x + (size_t)row * EMBED;

        float4 v[3];
        float sum = 0.f, sq = 0.f;
#pragma unroll
        for (int i = 0; i < 3; ++i) {
            v[i] = ((const float4*)xr)[lt + i * 128];
            sum += v[i].x + v[i].y + v[i].z + v[i].w;
            sq  += v[i].x * v[i].x + v[i].y * v[i].y + v[i].z * v[i].z + v[i].w * v[i].w;
        }
#pragma unroll
        for (int off = 32; off > 0; off >>= 1) {
            sum += __shfl_down(sum, off);
            sq  += __shfl_down(sq, off);
        }
        __shared__ float s_sum[4], s_sq[4];
        const int wave = tid >> 6, lane = tid & 63;
        if (lane == 0) { s_sum[wave] = sum; s_sq[wave] = sq; }
        __syncthreads();
        const int wb = half << 1;
        const float mu  = (s_sum[wb] + s_sum[wb + 1]) * (1.f / EMBED);
        const float var = (s_sq[wb] + s_sq[wb + 1]) * (1.f / EMBED) - mu * mu;
        const float rs  = rsqrtf(var + 1e-5f);

        __hip_bfloat16* xo = xn + (size_t)row * EMBED;
#pragma unroll
        for (int i = 0; i < 3; ++i) {
            const int idx = lt + i * 128;
            float4 gv = ((const float4*)gamma)[idx];
            float4 bv = ((const float4*)beta)[idx];
            union { __hip_bfloat16 h4[4]; short4 s4; } u;
            u.h4[0] = __float2bfloat16((v[i].x - mu) * rs * gv.x + bv.x);
            u.h4[1] = __float2bfloat16((v[i].y - mu) * rs * gv.y + bv.y);
            u.h4[2] = __float2bfloat16((v[i].z - mu) * rs * gv.z + bv.z);
            u.h4[3] = __float2bfloat16((v[i].w - mu) * rs * gv.w + bv.w);
            ((short4*)xo)[idx] = u.s4;
        }
    } else {
        // ---- W conversion: only heads some batch actually selected (block-uniform) ----
        const int gid = (blockIdx.x - LN_BLOCKS) * 256 + tid;
        const int r = gid / 192;                 // padded row
        const int c = (gid - r * 192) * 8;       // col (8 elems / thread)
        const int region = (r < W1OFF) ? 0 : (r < W2OFF) ? 1 : 2;
        const int h0 = head_idx[0], h1 = head_idx[1];
        const int h2 = head_idx[2], h3 = head_idx[3];
        if (region != h0 && region != h1 && region != h2 && region != h3)
            return;                              // unused head: gemm never reads these rows
        const float* src = nullptr;
        if (region == 0)      { if (r < N0) src = W0 + (size_t)r * EMBED; }
        else if (region == 1) { int rr = r - W1OFF; if (rr < N1) src = W1 + (size_t)rr * EMBED; }
        else                  { int rr = r - W2OFF; if (rr < N2) src = W2 + (size_t)rr * EMBED; }
        union { __hip_bfloat16 h8[8]; int4 v4; } u;
        if (src) {
            float4 a = ((const float4*)(src + c))[0];
            float4 b = ((const float4*)(src + c))[1];
            u.h8[0] = __float2bfloat16(a.x); u.h8[1] = __float2bfloat16(a.y);
            u.h8[2] = __float2bfloat16(a.z); u.h8[3] = __float2bfloat16(a.w);
            u.h8[4] = __float2bfloat16(b.x); u.h8[5] = __float2bfloat16(b.y);
            u.h8[6] = __float2bfloat16(b.z); u.h8[7] = __float2bfloat16(b.w);
        } else {
            u.v4 = make_int4(0, 0, 0, 0);
        }
        *(int4*)(wpad + (size_t)r * EMBED + c) = u.v4;
    }
}

// ---- 2) bf16 MFMA GEMM (128x128 tiles, BK=128, compacted) + bias + softplus ----
// ids 0..R-1: real tiles. ids >= R: zero-fill invalid col ranges (backfill idle CUs).
__global__ __launch_bounds__(256, 2) void head_gemm(
    const __hip_bfloat16* __restrict__ xn,   // (4*896, 1536)
    const __hip_bfloat16* __restrict__ wpad, // (7168, 1536) padded bf16
    const float* __restrict__ b0, const float* __restrict__ b1,
    const float* __restrict__ b2,
    const int* __restrict__ head_idx,
    float* __restrict__ out)                 // (4, 896, 5313)
{
    const int h0 = head_idx[0], h1 = head_idx[1];
    const int h2 = head_idx[2], h3 = head_idx[3];
    const int t0 = tiles_of(h0) * 7, t1 = tiles_of(h1) * 7;
    const int t2 = tiles_of(h2) * 7, t3 = tiles_of(h3) * 7;
    const int R = t0 + t1 + t2 + t3;
    const int tid = threadIdx.x;

    if ((int)blockIdx.x >= R) {
        // ---- zero-fill: strided rows over the invalid column ranges ----
        const int j = blockIdx.x - R;
        const int ZB = GEMM_GRID - R;            // >=104 whenever zf is needed
        for (int row = j; row < 4 * SEQ; row += ZB) {
            const int b = row / SEQ;
            const int h = (b == 0) ? h0 : (b == 1) ? h1 : (b == 2) ? h2 : h3;
            const int n = nrows_of(h);
            if (n >= NOUT) continue;
            float* o = out + (size_t)row * NOUT;
            const int pre0 = (4 - (int)(((size_t)row * NOUT + n) & 3)) & 3;
            const int pre_end = min(n + pre0, NOUT);
            for (int c = n + tid; c < pre_end; c += 256) o[c] = 0.f;
            const int nvec = (NOUT - pre_end) >> 2;
            const float4 z = make_float4(0.f, 0.f, 0.f, 0.f);
            float4* ov = (float4*)(o + pre_end);
            for (int i = tid; i < nvec; i += 256) ov[i] = z;
            for (int c = pre_end + (nvec << 2) + tid; c < NOUT; c += 256) o[c] = 0.f;
        }
        return;
    }

    int rem = blockIdx.x, b;
    if (rem < t0)                { b = 0; }
    else if (rem < t0 + t1)      { b = 1; rem -= t0; }
    else if (rem < t0 + t1 + t2) { b = 2; rem -= t0 + t1; }
    else                         { b = 3; rem -= t0 + t1 + t2; }

    const int h = (b == 0) ? h0 : (b == 1) ? h1 : (b == 2) ? h2 : h3;
    const int ntc = tiles_of(h);
    const int mt = rem / ntc;                    // 0..6 (128-row M tiles)
    const int nt = rem - mt * ntc;               // nt fastest: consecutive ids share A
    const int nrows = nrows_of(h);
    const int wbase = (h == 0) ? W0OFF : (h == 1) ? W1OFF : W2OFF;

    const int col0 = nt * 128;
    float* outb = out + ((size_t)b * SEQ + (size_t)mt * 128) * NOUT;

    __shared__ __hip_bfloat16 As[128 * BK];   // 32 KB
    __shared__ __hip_bfloat16 Bs[128 * BK];   // 32 KB
    const __hip_bfloat16* Ab = xn + ((size_t)b * SEQ + (size_t)mt * 128) * EMBED;
    const __hip_bfloat16* Bb = wpad + (size_t)(wbase + col0) * EMBED;

    const int wave = tid >> 6, lane = tid & 63;
    const int wm = wave >> 1, wn = wave & 1;         // 2x2 waves of 64x64
    const int fm = lane & 15, quad = lane >> 4;

    f32x4 acc[4][4] = {};

    for (int kt = 0; kt < EMBED / BK; ++kt) {        // 12 iterations
        const int k0 = kt * BK;
        __syncthreads();                             // prev readers done
#pragma unroll
        for (int i = 0; i < 8; ++i) {                // stage A: 128x128 bf16 (2048 chunks)
            const int c = tid + i * 256;             // LDS chunk idx (16B each)
            const int arow = c >> 4;
            const int kc = (c & 15) ^ (arow & 15);   // xor-swizzled k-chunk (16 slots)
            gload_lds16(Ab + (size_t)arow * EMBED + k0 + kc * 8, As + c * 8);
        }
#pragma unroll
        for (int i = 0; i < 8; ++i) {                // stage B: 128x128 bf16
            const int c = tid + i * 256;
            const int brow = c >> 4;
            const int kc = (c & 15) ^ (brow & 15);
            gload_lds16(Bb + (size_t)brow * EMBED + k0 + kc * 8, Bs + c * 8);
        }
        __syncthreads();                             // drains vmcnt before barrier
#pragma unroll
        for (int ks = 0; ks < 4; ++ks) {             // 4 x K32 sub-steps
            bf16x8 af[4], bfr[4];
#pragma unroll
            for (int i = 0; i < 4; ++i)
                af[i] = *(const bf16x8*)&As[(wm * 64 + i * 16 + fm) * BK +
                                            (((ks << 2) + quad) ^ fm) * 8];
#pragma unroll
            for (int j = 0; j < 4; ++j)
                bfr[j] = *(const bf16x8*)&Bs[(wn * 64 + j * 16 + fm) * BK +
                                             (((ks << 2) + quad) ^ fm) * 8];
#pragma unroll
            for (int i = 0; i < 4; ++i)
#pragma unroll
                for (int j = 0; j < 4; ++j)
                    acc[i][j] = __builtin_amdgcn_mfma_f32_16x16x32_bf16(
                        af[i], bfr[j], acc[i][j], 0, 0, 0);
        }
    }

    // epilogue: bias + softplus; store ONLY valid cols (zero region owned by zf)
    const float* bias = (h == 1) ? b1 : (h == 2) ? b2 : b0;
#pragma unroll
    for (int j = 0; j < 4; ++j) {
        const int lcol = col0 + wn * 64 + j * 16 + fm;
        const bool valid = lcol < nrows;
        const float bv = valid ? bias[lcol] : 0.f;
#pragma unroll
        for (int i = 0; i < 4; ++i) {
            const int rbase = wm * 64 + i * 16 + quad * 4;
#pragma unroll
            for (int r = 0; r < 4; ++r) {
                const float v = acc[i][j][r] + bv;
                // softplus: max(v,0) + log(1 + exp(-|v|)) — overflow-safe
                const float sp = fmaxf(v, 0.f) + __logf(1.f + __expf(-fabsf(v)));
                if (valid) outb[(size_t)(rbase + r) * NOUT + lcol] = sp;
            }
        }
    }
}

extern "C" void kernel_launch(void* const* d_in, const int* in_sizes, int n_in,
                              void* d_out, int out_size, void* d_ws, size_t ws_size,
                              hipStream_t stream) {
    const float* x   = (const float*)d_in[0];
    const int* hidx  = (const int*)d_in[1];
    const float* g0  = (const float*)d_in[2];
    const float* be0 = (const float*)d_in[3];
    const float* W0  = (const float*)d_in[4];
    const float* b0  = (const float*)d_in[5];
    const float* g1  = (const float*)d_in[6];
    const float* be1 = (const float*)d_in[7];
    const float* W1  = (const float*)d_in[8];
    const float* b1  = (const float*)d_in[9];
    const float* g2  = (const float*)d_in[10];
    const float* be2 = (const float*)d_in[11];
    const float* W2  = (const float*)d_in[12];
    const float* b2  = (const float*)d_in[13];
    float* out = (float*)d_out;

    // workspace layout
    const size_t XN_BYTES = (size_t)4 * SEQ * EMBED * 2;            // 11,010,048
    __hip_bfloat16* xn   = (__hip_bfloat16*)d_ws;
    __hip_bfloat16* wpad = (__hip_bfloat16*)((char*)d_ws + XN_BYTES);

    prep_kernel<<<LN_BLOCKS + WC_BLOCKS, 256, 0, stream>>>(
        x, hidx, g0, be0, g1, be1, g2, be2, W0, W1, W2, xn, wpad);
    head_gemm<<<GEMM_GRID, 256, 0, stream>>>(xn, wpad, b0, b1, b2, hidx, out);
}